// Round 15
// baseline (41.930 us; speedup 1.0000x reference)
//
#include <hip/hip_runtime.h>
#include <stdint.h>

#define HV 384
#define WV 384
#define HF 96
#define WF 96
#define NC 128
#define NB 32
#define NSTORM 50
#define TFRAMES 12
#define MIN_INT 0.3f
#define THOT 0.999f           // hot-key threshold; E[hot/batch] ~ 143 >> 50

// peak tile geometry (64x64 tiles: halo amp 1.11x, half the blocks of 32x64)
#define TW 64
#define TH 64
#define GX (WV / TW)          // 6
#define GY (HV / TH)          // 6
#define GT (GX * GY)          // 36 tiles per batch (<= 64: single-wave scans)
#define LCAP 384              // >= no-ties peak bound on 64x64 (17^2=289)

// selection
#define HCAP 1024             // hot staging (expected ~143)
// projection
#define SPB 10
#define NGRP (NSTORM / SPB)   // 5 groups per batch
#define NPROJ (NB * NGRP)     // 160 blocks (single block-wave on 256 CUs)

__device__ __forceinline__ int reflect_idx(int g, int n) {
    if (g < 0) return -g - 1;
    if (g >= n) return 2 * n - 1 - g;
    return g;
}

// ---- slow scalar peak predicate, used only on the dead fallback path
__device__ __forceinline__ bool is_peak(const float* __restrict__ vb, int p) {
    int i = p / WV, j = p % WV;
    float v = vb[p];
    if (!(v > MIN_INT)) return false;
    for (int dr = -4; dr <= 3; ++dr) {
        const float* row = vb + reflect_idx(i + dr, HV) * WV;
        for (int dc = -4; dc <= 3; ++dc)
            if (row[reflect_idx(j + dc, WV)] > v) return false;
    }
    return true;
}

// ---- kernel 1: separable 8x8 max filter; per-tile slots, keys partitioned
// hot-first (v >= THOT). tcnt packs (hot<<16)|total; every slot written every
// launch (no atomics, no memset). key = bits(v)<<32 | ~idx — strict total
// order; any hot key > any cold key, so top-50(hot) == top-50 when hot>=50.
__global__ void peak_kernel(const float* __restrict__ vil,
                            uint64_t* __restrict__ cand,
                            int* __restrict__ tcnt) {
    __shared__ __align__(16) float A[TH + 7][TW + 8];  // 71x72 tile + halo
    __shared__ float Bm[TH + 7][TW];                   // horizontal max
    __shared__ uint64_t hkeys[LCAP];
    __shared__ uint64_t ckeys[LCAP];
    __shared__ int hcnt, ccnt;

    int b = blockIdx.z, bx = blockIdx.x;
    int tx0 = bx * TW, ty0 = blockIdx.y * TH;
    int tile = blockIdx.y * GX + bx;
    int tid = threadIdx.x;                 // 256 threads
    const float* vb = vil + ((size_t)b * TFRAMES + (TFRAMES - 1)) * (HV * WV);

    if (tid == 0) { hcnt = 0; ccnt = 0; }

    // float4 staging; row reflect is pointer-only, keeps 16B alignment.
    int c0   = (bx == 0) ? 0 : tx0 - 4;               // multiple of 4
    int nf4  = (bx == 0 || bx == GX - 1) ? 17 : 18;
    int aoff = c0 - (tx0 - 4);                        // 0 or 4
    for (int k = tid; k < (TH + 7) * nf4; k += 256) {
        int r = k / nf4, q = k - r * nf4;
        int gr = reflect_idx(ty0 + r - 4, HV);
        float4 vv = *(const float4*)(vb + (size_t)gr * WV + c0 + 4 * q);
        *(float4*)&A[r][aoff + 4 * q] = vv;
    }
    int nl = aoff;
    int rstart = aoff + 4 * nf4;
    int nr = 71 - rstart; if (nr < 0) nr = 0;
    int ns = nl + nr;
    if (ns) for (int k = tid; k < (TH + 7) * ns; k += 256) {
        int r = k / ns, s = k - r * ns;
        int c = (s < nl) ? s : rstart + (s - nl);
        int gr = reflect_idx(ty0 + r - 4, HV);
        int gc = reflect_idx(tx0 + c - 4, WV);
        A[r][c] = vb[(size_t)gr * WV + gc];
    }
    __syncthreads();

    // horizontal: Bm[r][c] = max(A[r][c..c+7])
    for (int k = tid; k < (TH + 7) * TW; k += 256) {
        int r = k / TW, c = k % TW;
        float m = A[r][c];
        #pragma unroll
        for (int d = 1; d < 8; ++d) m = fmaxf(m, A[r][c + d]);
        Bm[r][c] = m;
    }
    __syncthreads();

    // vertical + predicate
    for (int k = tid; k < TH * TW; k += 256) {
        int r = k / TW, c = k % TW;
        float v = A[r + 4][c + 4];
        if (v > MIN_INT) {
            float m = Bm[r][c];
            #pragma unroll
            for (int d = 1; d < 8; ++d) m = fmaxf(m, Bm[r + d][c]);
            if (m <= v) {                  // window max == v -> peak
                int p = (ty0 + r) * WV + (tx0 + c);
                uint64_t key = ((uint64_t)__float_as_uint(v) << 32)
                             | (uint64_t)(0xFFFFFFFFu - (uint32_t)p);
                if (v >= THOT) {
                    int pos = atomicAdd(&hcnt, 1);
                    if (pos < LCAP) hkeys[pos] = key;
                } else {
                    int pos = atomicAdd(&ccnt, 1);
                    if (pos < LCAP) ckeys[pos] = key;
                }
            }
        }
    }
    __syncthreads();

    int nh = hcnt < LCAP ? hcnt : LCAP;
    int nc = ccnt < LCAP - nh ? ccnt : LCAP - nh;
    if (tid == 0) tcnt[b * GT + tile] = (nh << 16) | (nh + nc);
    uint64_t* dst = cand + (size_t)(b * GT + tile) * LCAP;
    for (int k = tid; k < nh; k += 256) dst[k] = hkeys[k];
    for (int k = tid; k < nc; k += 256) dst[nh + k] = ckeys[k];
}

// ---- kernel 2: 160 blocks; block = (batch b, storm-group of 10).
// Redundant per-block select (deterministic): single-wave scan of 36 hot
// counts, gather ~143 hot keys flat into LDS, rank O(H^2), write winners to
// rank. Then project the block's 10 storms.
__global__ void select_project_kernel(const uint64_t* __restrict__ cand,
                                      const int* __restrict__ tcnt,
                                      const float* __restrict__ vil,
                                      const float* __restrict__ features,
                                      const float* __restrict__ proj_w,
                                      const float* __restrict__ proj_b,
                                      float* __restrict__ out) {
    __shared__ uint64_t hot[HCAP];             // 8 KB
    __shared__ int hoffs[GT + 1];
    __shared__ int toffs[GT + 1];
    __shared__ int sel_idx_s[NSTORM];
    __shared__ int sel_valid_s[NSTORM];
    __shared__ uint64_t wred[4];
    __shared__ uint64_t bcast;
    __shared__ __align__(16) float g[SPB][NC]; // 5 KB

    int blk = blockIdx.x;
    int b = blk / NGRP;
    int grp = blk % NGRP;
    int tid = threadIdx.x;                     // 256
    const uint64_t* cb = cand + (size_t)b * GT * LCAP;

    int packed = (tid < GT) ? tcnt[b * GT + tid] : 0;

    // single-wave inclusive scan of hot counts (GT=36 <= 64 lanes)
    if (tid < 64) {
        int s = packed >> 16;
        #pragma unroll
        for (int off = 1; off < 64; off <<= 1) {
            int u = __shfl(s, (tid - off) & 63);
            if (tid >= off) s += u;
        }
        if (tid == 0) hoffs[0] = 0;
        if (tid < GT) hoffs[tid + 1] = s;
    }
    __syncthreads();
    int H = hoffs[GT];

    if (H >= NSTORM && H <= HCAP) {
        // ---- fast path (live): top-50 = top-50 of hot keys
        for (int hi = tid; hi < H; hi += 256) {
            int lo = 0, hi2 = GT;
            while (hi2 - lo > 1) { int mid = (lo + hi2) >> 1;
                                   if (hoffs[mid] <= hi) lo = mid; else hi2 = mid; }
            hot[hi] = cb[(size_t)lo * LCAP + (hi - hoffs[lo])];
        }
        __syncthreads();
        for (int i = tid; i < H; i += 256) {
            uint64_t ki = hot[i];
            int r = 0;
            for (int j = 0; j < H; ++j) r += (hot[j] > ki);
            if (r < NSTORM) {
                sel_idx_s[r] = (int)(~(uint32_t)(ki & 0xFFFFFFFFu));
                sel_valid_s[r] = 1;
            }
        }
    } else {
        // ---- dead safety path: scan totals, exact 50-round rescan
        if (tid < 64) {
            int s = packed & 0xFFFF;
            #pragma unroll
            for (int off = 1; off < 64; off <<= 1) {
                int u = __shfl(s, (tid - off) & 63);
                if (tid >= off) s += u;
            }
            if (tid == 0) toffs[0] = 0;
            if (tid < GT) toffs[tid + 1] = s;
        }
        __syncthreads();
        int n = toffs[GT];
        int target = n < NSTORM ? n : NSTORM;

        uint64_t prev = ~0ull;
        for (int t = 0; t < target; ++t) {
            uint64_t best = 0;
            for (int gi = tid; gi < n; gi += 256) {
                int lo = 0, hi2 = GT;
                while (hi2 - lo > 1) { int mid = (lo + hi2) >> 1;
                                       if (toffs[mid] <= gi) lo = mid; else hi2 = mid; }
                uint64_t key = cb[(size_t)lo * LCAP + (gi - toffs[lo])];
                if (key < prev && key > best) best = key;
            }
            #pragma unroll
            for (int off = 32; off > 0; off >>= 1) {
                uint64_t o = __shfl_xor(best, off);
                if (o > best) best = o;
            }
            if ((tid & 63) == 0) wred[tid >> 6] = best;
            __syncthreads();
            if (tid == 0) {
                uint64_t w = wred[0];
                #pragma unroll
                for (int i = 1; i < 4; ++i) if (wred[i] > w) w = wred[i];
                bcast = w;
                sel_idx_s[t] = (int)(~(uint32_t)(w & 0xFFFFFFFFu));
                sel_valid_s[t] = 1;
            }
            __syncthreads();
            prev = bcast;
        }
        __syncthreads();
        // <50 peaks -> ascending non-peak indices; none -> center
        if (tid == 0 && target < NSTORM) {
            const float* vb = vil + ((size_t)b * TFRAMES + (TFRAMES - 1)) * (HV * WV);
            int f = 0;
            for (int t = target; t < NSTORM; ++t) {
                while (f < HV * WV && is_peak(vb, f)) ++f;
                sel_idx_s[t] = f; sel_valid_s[t] = 0; ++f;
            }
            if (n == 0) { sel_idx_s[0] = (HV / 2) * WV + (WV / 2); sel_valid_s[0] = 1; }
        }
    }
    __syncthreads();

    // positions / valid written once per batch (group 0 only)
    if (grp == 0 && tid < NSTORM) {
        int idx = sel_idx_s[tid], vld = sel_valid_s[tid];
        int y = idx / WV, x = idx % WV;
        int yf = y >> 2; if (yf > HF - 1) yf = HF - 1;
        int xf = x >> 2; if (xf > WF - 1) xf = WF - 1;
        float* pos_out   = out + (size_t)NB * NSTORM * NC;
        float* valid_out = pos_out + (size_t)NB * NSTORM * 2;
        pos_out[(b * NSTORM + tid) * 2 + 0] = (float)yf;
        pos_out[(b * NSTORM + tid) * 2 + 1] = (float)xf;
        valid_out[b * NSTORM + tid] = vld ? 1.f : 0.f;
    }

    // ---- project my 10 storms: gather (256 threads) + matvec (128)
    for (int q = tid; q < SPB * NC; q += 256) {
        int s = q >> 7, c = q & 127;
        int idx = sel_idx_s[grp * SPB + s];
        int y = idx / WV, x = idx % WV;
        int yf = y >> 2; if (yf > HF - 1) yf = HF - 1;
        int xf = x >> 2; if (xf > WF - 1) xf = WF - 1;
        g[s][c] = features[((size_t)b * NC + c) * (HF * WF) + yf * WF + xf];
    }
    __syncthreads();

    if (tid < NC) {
        int d = tid;
        const float4* w4 = (const float4*)(proj_w + (size_t)d * NC);
        float acc[SPB];
        #pragma unroll
        for (int s = 0; s < SPB; ++s) acc[s] = 0.f;
        for (int q = 0; q < 32; ++q) {
            float4 wv = w4[q];
            #pragma unroll
            for (int s = 0; s < SPB; ++s) {
                float4 gv = *(const float4*)&g[s][4 * q];
                acc[s] += gv.x * wv.x;
                acc[s] += gv.y * wv.y;
                acc[s] += gv.z * wv.z;
                acc[s] += gv.w * wv.w;
            }
        }
        float bias = proj_b[d];
        #pragma unroll
        for (int s = 0; s < SPB; ++s) {
            int m = grp * SPB + s;
            out[((size_t)b * NSTORM + m) * NC + d] =
                sel_valid_s[m] ? (acc[s] + bias) : 0.f;
        }
    }
}

extern "C" void kernel_launch(void* const* d_in, const int* in_sizes, int n_in,
                              void* d_out, int out_size, void* d_ws, size_t ws_size,
                              hipStream_t stream) {
    const float* features = (const float*)d_in[0];
    const float* vil      = (const float*)d_in[1];
    const float* proj_w   = (const float*)d_in[2];
    const float* proj_b   = (const float*)d_in[3];
    float* out = (float*)d_out;

    uint8_t* ws = (uint8_t*)d_ws;
    int* tcnt      = (int*)ws;                        // 32*36 ints, all written
    uint64_t* cand = (uint64_t*)(ws + 32768);         // 32*36*384 u64 = 3.5 MB

    dim3 gA(GX, GY, NB);                   // 6 x 6 x 32
    peak_kernel<<<gA, 256, 0, stream>>>(vil, cand, tcnt);
    select_project_kernel<<<NPROJ, 256, 0, stream>>>(cand, tcnt, vil, features,
                                                     proj_w, proj_b, out);
}

// Round 16
// 38.676 us; speedup vs baseline: 1.0841x; 1.0841x over previous
//
#include <hip/hip_runtime.h>
#include <stdint.h>

#define HV 384
#define WV 384
#define HF 96
#define WF 96
#define NC 128
#define NB 32
#define NSTORM 50
#define TFRAMES 12
#define MIN_INT 0.3f
#define THOT 0.999f           // hot-key threshold; E[hot/batch] ~ 143 >> 50

// peak tile geometry (R14 config: best measured — 25.6 KB LDS, 6 blocks/CU)
#define TW 64
#define TH 32
#define GX (WV / TW)          // 6
#define GY (HV / TH)          // 12
#define GT (GX * GY)          // 72 tiles per batch
#define LCAP 256              // >= provable max peaks per tile (~153)

// selection
#define HCAP 1024             // hot staging (expected ~143)
// projection
#define SPB 10
#define NGRP (NSTORM / SPB)   // 5 groups per batch
#define NPROJ (NB * NGRP)     // 160 blocks (single block-wave on 256 CUs)

__device__ __forceinline__ int reflect_idx(int g, int n) {
    if (g < 0) return -g - 1;
    if (g >= n) return 2 * n - 1 - g;
    return g;
}

// ---- slow scalar peak predicate, used only on the dead fallback path
__device__ __forceinline__ bool is_peak(const float* __restrict__ vb, int p) {
    int i = p / WV, j = p % WV;
    float v = vb[p];
    if (!(v > MIN_INT)) return false;
    for (int dr = -4; dr <= 3; ++dr) {
        const float* row = vb + reflect_idx(i + dr, HV) * WV;
        for (int dc = -4; dc <= 3; ++dc)
            if (row[reflect_idx(j + dc, WV)] > v) return false;
    }
    return true;
}

// ---- kernel 1: separable 8x8 max filter; pairwise-shared-core passes
// (adjacent outputs share 7/8 window elements -> compute core once: 8 fmax
// + 9 LDS reads per OUTPUT PAIR, exact, no extra LDS/barriers). Keys
// partitioned hot-first (v >= THOT); tcnt packs (hot<<16)|total, every slot
// written every launch. key = bits(v)<<32 | ~idx — strict total order.
__global__ void peak_kernel(const float* __restrict__ vil,
                            uint64_t* __restrict__ cand,
                            int* __restrict__ tcnt) {
    __shared__ __align__(16) float A[TH + 7][TW + 8];  // 39x72 tile + halo
    __shared__ float Bm[TH + 7][TW];                   // horizontal max
    __shared__ uint64_t hkeys[LCAP];
    __shared__ uint64_t ckeys[LCAP];
    __shared__ int hcnt, ccnt;

    int b = blockIdx.z, bx = blockIdx.x;
    int tx0 = bx * TW, ty0 = blockIdx.y * TH;
    int tile = blockIdx.y * GX + bx;
    int tid = threadIdx.x;                 // 256 threads
    const float* vb = vil + ((size_t)b * TFRAMES + (TFRAMES - 1)) * (HV * WV);

    if (tid == 0) { hcnt = 0; ccnt = 0; }

    // float4 staging; row reflect is pointer-only, keeps 16B alignment.
    int c0   = (bx == 0) ? 0 : tx0 - 4;               // multiple of 4
    int nf4  = (bx == 0 || bx == GX - 1) ? 17 : 18;
    int aoff = c0 - (tx0 - 4);                        // 0 or 4
    for (int k = tid; k < (TH + 7) * nf4; k += 256) {
        int r = k / nf4, q = k - r * nf4;
        int gr = reflect_idx(ty0 + r - 4, HV);
        float4 vv = *(const float4*)(vb + (size_t)gr * WV + c0 + 4 * q);
        *(float4*)&A[r][aoff + 4 * q] = vv;
    }
    int nl = aoff;
    int rstart = aoff + 4 * nf4;
    int nr = 71 - rstart; if (nr < 0) nr = 0;
    int ns = nl + nr;
    if (ns) for (int k = tid; k < (TH + 7) * ns; k += 256) {
        int r = k / ns, s = k - r * ns;
        int c = (s < nl) ? s : rstart + (s - nl);
        int gr = reflect_idx(ty0 + r - 4, HV);
        int gc = reflect_idx(tx0 + c - 4, WV);
        A[r][c] = vb[(size_t)gr * WV + gc];
    }
    __syncthreads();

    // horizontal: output pair (c, c+1); shared core = max(A[c+1..c+7])
    for (int k = tid; k < (TH + 7) * (TW / 2); k += 256) {
        int r = k / (TW / 2), c = 2 * (k % (TW / 2));
        float s = A[r][c + 1];
        #pragma unroll
        for (int d = 2; d <= 7; ++d) s = fmaxf(s, A[r][c + d]);
        Bm[r][c]     = fmaxf(A[r][c], s);
        Bm[r][c + 1] = fmaxf(s, A[r][c + 8]);
    }
    __syncthreads();

    // vertical + predicate: output pair (r, r+1); core = max(Bm[r+1..r+7])
    for (int k = tid; k < (TH / 2) * TW; k += 256) {
        int r = 2 * (k / TW), c = k % TW;
        float s = Bm[r + 1][c];
        #pragma unroll
        for (int d = 2; d <= 7; ++d) s = fmaxf(s, Bm[r + d][c]);
        #pragma unroll
        for (int half = 0; half < 2; ++half) {
            int rr = r + half;
            float v = A[rr + 4][c + 4];
            if (v > MIN_INT) {
                float m = half ? fmaxf(s, Bm[r + 8][c]) : fmaxf(Bm[r][c], s);
                if (m <= v) {              // window max == v -> peak
                    int p = (ty0 + rr) * WV + (tx0 + c);
                    uint64_t key = ((uint64_t)__float_as_uint(v) << 32)
                                 | (uint64_t)(0xFFFFFFFFu - (uint32_t)p);
                    if (v >= THOT) {
                        int pos = atomicAdd(&hcnt, 1);
                        if (pos < LCAP) hkeys[pos] = key;
                    } else {
                        int pos = atomicAdd(&ccnt, 1);
                        if (pos < LCAP) ckeys[pos] = key;
                    }
                }
            }
        }
    }
    __syncthreads();

    int nh = hcnt < LCAP ? hcnt : LCAP;
    int nc = ccnt < LCAP - nh ? ccnt : LCAP - nh;
    if (tid == 0) tcnt[b * GT + tile] = (nh << 16) | (nh + nc);
    uint64_t* dst = cand + (size_t)(b * GT + tile) * LCAP;
    for (int k = tid; k < nh; k += 256) dst[k] = hkeys[k];
    for (int k = tid; k < nc; k += 256) dst[nh + k] = ckeys[k];
}

// ---- kernel 2: 160 blocks; block = (batch b, storm-group of 10).
// Redundant per-block select (deterministic): scan 72 hot counts, gather
// ~143 hot keys flat into LDS, rank O(H^2), write winners to rank.
// Then project the block's 10 storms.  (R14 version, unchanged.)
__global__ void select_project_kernel(const uint64_t* __restrict__ cand,
                                      const int* __restrict__ tcnt,
                                      const float* __restrict__ vil,
                                      const float* __restrict__ features,
                                      const float* __restrict__ proj_w,
                                      const float* __restrict__ proj_b,
                                      float* __restrict__ out) {
    __shared__ uint64_t hot[HCAP];             // 8 KB
    __shared__ int sc[128];
    __shared__ int hoffs[GT + 1];
    __shared__ int toffs[GT + 1];
    __shared__ int sel_idx_s[NSTORM];
    __shared__ int sel_valid_s[NSTORM];
    __shared__ uint64_t wred[4];
    __shared__ uint64_t bcast;
    __shared__ __align__(16) float g[SPB][NC]; // 5 KB

    int blk = blockIdx.x;
    int b = blk / NGRP;
    int grp = blk % NGRP;
    int tid = threadIdx.x;                     // 256
    const uint64_t* cb = cand + (size_t)b * GT * LCAP;

    int packed = (tid < GT) ? tcnt[b * GT + tid] : 0;
    int myhot = packed >> 16, mytot = packed & 0xFFFF;

    // scan hot counts (Hillis-Steele over 128; GT=72)
    if (tid < 128) sc[tid] = (tid < GT) ? myhot : 0;
    __syncthreads();
    #pragma unroll
    for (int off = 1; off < 128; off <<= 1) {
        int v = 0;
        if (tid < 128 && tid >= off) v = sc[tid - off];
        __syncthreads();
        if (tid < 128) sc[tid] += v;
        __syncthreads();
    }
    if (tid == 0) hoffs[0] = 0;
    if (tid < GT) hoffs[tid + 1] = sc[tid];
    __syncthreads();
    int H = hoffs[GT];

    // scan total counts
    if (tid < 128) sc[tid] = (tid < GT) ? mytot : 0;
    __syncthreads();
    #pragma unroll
    for (int off = 1; off < 128; off <<= 1) {
        int v = 0;
        if (tid < 128 && tid >= off) v = sc[tid - off];
        __syncthreads();
        if (tid < 128) sc[tid] += v;
        __syncthreads();
    }
    if (tid == 0) toffs[0] = 0;
    if (tid < GT) toffs[tid + 1] = sc[tid];
    __syncthreads();
    int n = toffs[GT];
    int target = n < NSTORM ? n : NSTORM;

    if (H >= target && H <= HCAP && n > 0) {
        // ---- fast path: gather hot keys flat (hot keys are at slot front)
        for (int hi = tid; hi < H; hi += 256) {
            int lo = 0, hi2 = GT;
            while (hi2 - lo > 1) { int mid = (lo + hi2) >> 1;
                                   if (hoffs[mid] <= hi) lo = mid; else hi2 = mid; }
            hot[hi] = cb[(size_t)lo * LCAP + (hi - hoffs[lo])];
        }
        __syncthreads();
        // ---- rank (keys unique; hot set contains all keys >= any hot key)
        for (int i = tid; i < H; i += 256) {
            uint64_t ki = hot[i];
            int r = 0;
            for (int j = 0; j < H; ++j) r += (hot[j] > ki);
            if (r < target) {
                sel_idx_s[r] = (int)(~(uint32_t)(ki & 0xFFFFFFFFu));
                sel_valid_s[r] = 1;
            }
        }
    } else if (n > 0) {
        // dead safety path (H < target or H > HCAP): 50-round exact rescan
        uint64_t prev = ~0ull;
        for (int t = 0; t < target; ++t) {
            uint64_t best = 0;
            for (int gi = tid; gi < n; gi += 256) {
                int lo = 0, hi2 = GT;
                while (hi2 - lo > 1) { int mid = (lo + hi2) >> 1;
                                       if (toffs[mid] <= gi) lo = mid; else hi2 = mid; }
                uint64_t key = cb[(size_t)lo * LCAP + (gi - toffs[lo])];
                if (key < prev && key > best) best = key;
            }
            #pragma unroll
            for (int off = 32; off > 0; off >>= 1) {
                uint64_t o = __shfl_xor(best, off);
                if (o > best) best = o;
            }
            if ((tid & 63) == 0) wred[tid >> 6] = best;
            __syncthreads();
            if (tid == 0) {
                uint64_t w = wred[0];
                #pragma unroll
                for (int i = 1; i < 4; ++i) if (wred[i] > w) w = wred[i];
                bcast = w;
                sel_idx_s[t] = (int)(~(uint32_t)(w & 0xFFFFFFFFu));
                sel_valid_s[t] = 1;
            }
            __syncthreads();
            prev = bcast;
        }
    }
    __syncthreads();

    // dead fallback: <50 peaks -> ascending non-peak indices; none -> center
    if (tid == 0 && target < NSTORM) {
        const float* vb = vil + ((size_t)b * TFRAMES + (TFRAMES - 1)) * (HV * WV);
        int f = 0;
        for (int t = target; t < NSTORM; ++t) {
            while (f < HV * WV && is_peak(vb, f)) ++f;
            sel_idx_s[t] = f; sel_valid_s[t] = 0; ++f;
        }
        if (n == 0) { sel_idx_s[0] = (HV / 2) * WV + (WV / 2); sel_valid_s[0] = 1; }
    }
    __syncthreads();

    // positions / valid written once per batch (group 0 only)
    if (grp == 0 && tid < NSTORM) {
        int idx = sel_idx_s[tid], vld = sel_valid_s[tid];
        int y = idx / WV, x = idx % WV;
        int yf = y >> 2; if (yf > HF - 1) yf = HF - 1;
        int xf = x >> 2; if (xf > WF - 1) xf = WF - 1;
        float* pos_out   = out + (size_t)NB * NSTORM * NC;
        float* valid_out = pos_out + (size_t)NB * NSTORM * 2;
        pos_out[(b * NSTORM + tid) * 2 + 0] = (float)yf;
        pos_out[(b * NSTORM + tid) * 2 + 1] = (float)xf;
        valid_out[b * NSTORM + tid] = vld ? 1.f : 0.f;
    }

    // ---- project my 10 storms: gather (256 threads) + matvec (128)
    for (int q = tid; q < SPB * NC; q += 256) {
        int s = q >> 7, c = q & 127;
        int idx = sel_idx_s[grp * SPB + s];
        int y = idx / WV, x = idx % WV;
        int yf = y >> 2; if (yf > HF - 1) yf = HF - 1;
        int xf = x >> 2; if (xf > WF - 1) xf = WF - 1;
        g[s][c] = features[((size_t)b * NC + c) * (HF * WF) + yf * WF + xf];
    }
    __syncthreads();

    if (tid < NC) {
        int d = tid;
        const float4* w4 = (const float4*)(proj_w + (size_t)d * NC);
        float acc[SPB];
        #pragma unroll
        for (int s = 0; s < SPB; ++s) acc[s] = 0.f;
        for (int q = 0; q < 32; ++q) {
            float4 wv = w4[q];
            #pragma unroll
            for (int s = 0; s < SPB; ++s) {
                float4 gv = *(const float4*)&g[s][4 * q];
                acc[s] += gv.x * wv.x;
                acc[s] += gv.y * wv.y;
                acc[s] += gv.z * wv.z;
                acc[s] += gv.w * wv.w;
            }
        }
        float bias = proj_b[d];
        #pragma unroll
        for (int s = 0; s < SPB; ++s) {
            int m = grp * SPB + s;
            out[((size_t)b * NSTORM + m) * NC + d] =
                sel_valid_s[m] ? (acc[s] + bias) : 0.f;
        }
    }
}

extern "C" void kernel_launch(void* const* d_in, const int* in_sizes, int n_in,
                              void* d_out, int out_size, void* d_ws, size_t ws_size,
                              hipStream_t stream) {
    const float* features = (const float*)d_in[0];
    const float* vil      = (const float*)d_in[1];
    const float* proj_w   = (const float*)d_in[2];
    const float* proj_b   = (const float*)d_in[3];
    float* out = (float*)d_out;

    uint8_t* ws = (uint8_t*)d_ws;
    int* tcnt      = (int*)ws;                        // 32*72 ints, all written
    uint64_t* cand = (uint64_t*)(ws + 32768);         // 32*72*256 u64 = 4.7 MB

    dim3 gA(GX, GY, NB);                   // 6 x 12 x 32
    peak_kernel<<<gA, 256, 0, stream>>>(vil, cand, tcnt);
    select_project_kernel<<<NPROJ, 256, 0, stream>>>(cand, tcnt, vil, features,
                                                     proj_w, proj_b, out);
}

// Round 17
// 37.370 us; speedup vs baseline: 1.1220x; 1.0349x over previous
//
#include <hip/hip_runtime.h>
#include <stdint.h>

#define HV 384
#define WV 384
#define HF 96
#define WF 96
#define NC 128
#define NB 32
#define NSTORM 50
#define TFRAMES 12
#define MIN_INT 0.3f
#define THOT 0.999f           // hot-key threshold; E[hot/batch] ~ 143 >> 50

// peak tile geometry (R14/R16 config: best measured)
#define TW 64
#define TH 32
#define GX (WV / TW)          // 6
#define GY (HV / TH)          // 12
#define GT (GX * GY)          // 72 tiles per batch
#define LCAP 256              // >= provable max peaks per tile (~153)

// selection
#define HCAP 1024             // hot staging (expected ~143)
// projection
#define SPB 10
#define NGRP (NSTORM / SPB)   // 5 groups per batch
#define NPROJ (NB * NGRP)     // 160 blocks (single block-wave on 256 CUs)

__device__ __forceinline__ int reflect_idx(int g, int n) {
    if (g < 0) return -g - 1;
    if (g >= n) return 2 * n - 1 - g;
    return g;
}

// ---- slow scalar peak predicate, used only on the dead fallback path
__device__ __forceinline__ bool is_peak(const float* __restrict__ vb, int p) {
    int i = p / WV, j = p % WV;
    float v = vb[p];
    if (!(v > MIN_INT)) return false;
    for (int dr = -4; dr <= 3; ++dr) {
        const float* row = vb + reflect_idx(i + dr, HV) * WV;
        for (int dc = -4; dc <= 3; ++dc)
            if (row[reflect_idx(j + dc, WV)] > v) return false;
    }
    return true;
}

// ---- kernel 1: separable 8x8 max filter; pairwise-shared-core passes
// (adjacent outputs share 7/8 window elements -> compute core once: 8 fmax
// + 9 LDS reads per OUTPUT PAIR, exact). Keys partitioned hot-first
// (v >= THOT); tcnt packs (hot<<16)|total, every slot written every launch.
// key = bits(v)<<32 | ~idx — strict total order.  (R16 version, unchanged.)
__global__ void peak_kernel(const float* __restrict__ vil,
                            uint64_t* __restrict__ cand,
                            int* __restrict__ tcnt) {
    __shared__ __align__(16) float A[TH + 7][TW + 8];  // 39x72 tile + halo
    __shared__ float Bm[TH + 7][TW];                   // horizontal max
    __shared__ uint64_t hkeys[LCAP];
    __shared__ uint64_t ckeys[LCAP];
    __shared__ int hcnt, ccnt;

    int b = blockIdx.z, bx = blockIdx.x;
    int tx0 = bx * TW, ty0 = blockIdx.y * TH;
    int tile = blockIdx.y * GX + bx;
    int tid = threadIdx.x;                 // 256 threads
    const float* vb = vil + ((size_t)b * TFRAMES + (TFRAMES - 1)) * (HV * WV);

    if (tid == 0) { hcnt = 0; ccnt = 0; }

    // float4 staging; row reflect is pointer-only, keeps 16B alignment.
    int c0   = (bx == 0) ? 0 : tx0 - 4;               // multiple of 4
    int nf4  = (bx == 0 || bx == GX - 1) ? 17 : 18;
    int aoff = c0 - (tx0 - 4);                        // 0 or 4
    for (int k = tid; k < (TH + 7) * nf4; k += 256) {
        int r = k / nf4, q = k - r * nf4;
        int gr = reflect_idx(ty0 + r - 4, HV);
        float4 vv = *(const float4*)(vb + (size_t)gr * WV + c0 + 4 * q);
        *(float4*)&A[r][aoff + 4 * q] = vv;
    }
    int nl = aoff;
    int rstart = aoff + 4 * nf4;
    int nr = 71 - rstart; if (nr < 0) nr = 0;
    int ns = nl + nr;
    if (ns) for (int k = tid; k < (TH + 7) * ns; k += 256) {
        int r = k / ns, s = k - r * ns;
        int c = (s < nl) ? s : rstart + (s - nl);
        int gr = reflect_idx(ty0 + r - 4, HV);
        int gc = reflect_idx(tx0 + c - 4, WV);
        A[r][c] = vb[(size_t)gr * WV + gc];
    }
    __syncthreads();

    // horizontal: output pair (c, c+1); shared core = max(A[c+1..c+7])
    for (int k = tid; k < (TH + 7) * (TW / 2); k += 256) {
        int r = k / (TW / 2), c = 2 * (k % (TW / 2));
        float s = A[r][c + 1];
        #pragma unroll
        for (int d = 2; d <= 7; ++d) s = fmaxf(s, A[r][c + d]);
        Bm[r][c]     = fmaxf(A[r][c], s);
        Bm[r][c + 1] = fmaxf(s, A[r][c + 8]);
    }
    __syncthreads();

    // vertical + predicate: output pair (r, r+1); core = max(Bm[r+1..r+7])
    for (int k = tid; k < (TH / 2) * TW; k += 256) {
        int r = 2 * (k / TW), c = k % TW;
        float s = Bm[r + 1][c];
        #pragma unroll
        for (int d = 2; d <= 7; ++d) s = fmaxf(s, Bm[r + d][c]);
        #pragma unroll
        for (int half = 0; half < 2; ++half) {
            int rr = r + half;
            float v = A[rr + 4][c + 4];
            if (v > MIN_INT) {
                float m = half ? fmaxf(s, Bm[r + 8][c]) : fmaxf(Bm[r][c], s);
                if (m <= v) {              // window max == v -> peak
                    int p = (ty0 + rr) * WV + (tx0 + c);
                    uint64_t key = ((uint64_t)__float_as_uint(v) << 32)
                                 | (uint64_t)(0xFFFFFFFFu - (uint32_t)p);
                    if (v >= THOT) {
                        int pos = atomicAdd(&hcnt, 1);
                        if (pos < LCAP) hkeys[pos] = key;
                    } else {
                        int pos = atomicAdd(&ccnt, 1);
                        if (pos < LCAP) ckeys[pos] = key;
                    }
                }
            }
        }
    }
    __syncthreads();

    int nh = hcnt < LCAP ? hcnt : LCAP;
    int nc = ccnt < LCAP - nh ? ccnt : LCAP - nh;
    if (tid == 0) tcnt[b * GT + tile] = (nh << 16) | (nh + nc);
    uint64_t* dst = cand + (size_t)(b * GT + tile) * LCAP;
    for (int k = tid; k < nh; k += 256) dst[k] = hkeys[k];
    for (int k = tid; k < nc; k += 256) dst[nh + k] = ckeys[k];
}

// ---- kernel 2: 160 blocks; block = (batch b, storm-group of 10).
// Redundant per-block select (deterministic). NEW: both prefix sums (hot &
// total) come from ONE single-wave shuffle scan of the PACKED counts —
// field sums max 72*256=18432 < 2^16, so no cross-field carry; 28 scan
// barriers -> 1. Then gather ~143 hot keys, rank O(H^2), project 10 storms.
__global__ void select_project_kernel(const uint64_t* __restrict__ cand,
                                      const int* __restrict__ tcnt,
                                      const float* __restrict__ vil,
                                      const float* __restrict__ features,
                                      const float* __restrict__ proj_w,
                                      const float* __restrict__ proj_b,
                                      float* __restrict__ out) {
    __shared__ uint64_t hot[HCAP];             // 8 KB
    __shared__ int hoffs[GT + 1];
    __shared__ int toffs[GT + 1];
    __shared__ int sel_idx_s[NSTORM];
    __shared__ int sel_valid_s[NSTORM];
    __shared__ uint64_t wred[4];
    __shared__ uint64_t bcast;
    __shared__ __align__(16) float g[SPB][NC]; // 5 KB

    int blk = blockIdx.x;
    int b = blk / NGRP;
    int grp = blk % NGRP;
    int tid = threadIdx.x;                     // 256
    const uint64_t* cb = cand + (size_t)b * GT * LCAP;

    // single-wave packed scan: lane l<36 owns tiles 2l, 2l+1 (GT=72)
    if (tid < 64) {
        int l = tid;
        int p0 = (l < GT / 2) ? tcnt[b * GT + 2 * l] : 0;
        int p1 = (l < GT / 2) ? tcnt[b * GT + 2 * l + 1] : 0;
        int pair = p0 + p1;
        int s = pair;
        #pragma unroll
        for (int off = 1; off < 64; off <<= 1) {
            int u = __shfl(s, (l - off) & 63);
            if (l >= off) s += u;
        }
        int excl = s - pair;                  // packed exclusive prefix
        if (l < GT / 2) {
            hoffs[2 * l]     = excl >> 16;           toffs[2 * l]     = excl & 0xFFFF;
            hoffs[2 * l + 1] = (excl + p0) >> 16;    toffs[2 * l + 1] = (excl + p0) & 0xFFFF;
        }
        if (l == GT / 2 - 1) { hoffs[GT] = s >> 16;  toffs[GT] = s & 0xFFFF; }
    }
    __syncthreads();
    int H = hoffs[GT];
    int n = toffs[GT];
    int target = n < NSTORM ? n : NSTORM;

    if (H >= target && H <= HCAP && n > 0) {
        // ---- fast path: gather hot keys flat (hot keys are at slot front)
        for (int hi = tid; hi < H; hi += 256) {
            int lo = 0, hi2 = GT;
            while (hi2 - lo > 1) { int mid = (lo + hi2) >> 1;
                                   if (hoffs[mid] <= hi) lo = mid; else hi2 = mid; }
            hot[hi] = cb[(size_t)lo * LCAP + (hi - hoffs[lo])];
        }
        __syncthreads();
        // ---- rank (keys unique; hot set contains all keys >= any hot key)
        for (int i = tid; i < H; i += 256) {
            uint64_t ki = hot[i];
            int r = 0;
            for (int j = 0; j < H; ++j) r += (hot[j] > ki);
            if (r < target) {
                sel_idx_s[r] = (int)(~(uint32_t)(ki & 0xFFFFFFFFu));
                sel_valid_s[r] = 1;
            }
        }
    } else if (n > 0) {
        // dead safety path (H < target or H > HCAP): 50-round exact rescan
        uint64_t prev = ~0ull;
        for (int t = 0; t < target; ++t) {
            uint64_t best = 0;
            for (int gi = tid; gi < n; gi += 256) {
                int lo = 0, hi2 = GT;
                while (hi2 - lo > 1) { int mid = (lo + hi2) >> 1;
                                       if (toffs[mid] <= gi) lo = mid; else hi2 = mid; }
                uint64_t key = cb[(size_t)lo * LCAP + (gi - toffs[lo])];
                if (key < prev && key > best) best = key;
            }
            #pragma unroll
            for (int off = 32; off > 0; off >>= 1) {
                uint64_t o = __shfl_xor(best, off);
                if (o > best) best = o;
            }
            if ((tid & 63) == 0) wred[tid >> 6] = best;
            __syncthreads();
            if (tid == 0) {
                uint64_t w = wred[0];
                #pragma unroll
                for (int i = 1; i < 4; ++i) if (wred[i] > w) w = wred[i];
                bcast = w;
                sel_idx_s[t] = (int)(~(uint32_t)(w & 0xFFFFFFFFu));
                sel_valid_s[t] = 1;
            }
            __syncthreads();
            prev = bcast;
        }
    }
    __syncthreads();

    // dead fallback: <50 peaks -> ascending non-peak indices; none -> center
    if (tid == 0 && target < NSTORM) {
        const float* vb = vil + ((size_t)b * TFRAMES + (TFRAMES - 1)) * (HV * WV);
        int f = 0;
        for (int t = target; t < NSTORM; ++t) {
            while (f < HV * WV && is_peak(vb, f)) ++f;
            sel_idx_s[t] = f; sel_valid_s[t] = 0; ++f;
        }
        if (n == 0) { sel_idx_s[0] = (HV / 2) * WV + (WV / 2); sel_valid_s[0] = 1; }
    }
    __syncthreads();

    // positions / valid written once per batch (group 0 only)
    if (grp == 0 && tid < NSTORM) {
        int idx = sel_idx_s[tid], vld = sel_valid_s[tid];
        int y = idx / WV, x = idx % WV;
        int yf = y >> 2; if (yf > HF - 1) yf = HF - 1;
        int xf = x >> 2; if (xf > WF - 1) xf = WF - 1;
        float* pos_out   = out + (size_t)NB * NSTORM * NC;
        float* valid_out = pos_out + (size_t)NB * NSTORM * 2;
        pos_out[(b * NSTORM + tid) * 2 + 0] = (float)yf;
        pos_out[(b * NSTORM + tid) * 2 + 1] = (float)xf;
        valid_out[b * NSTORM + tid] = vld ? 1.f : 0.f;
    }

    // ---- project my 10 storms: gather (256 threads) + matvec (128)
    for (int q = tid; q < SPB * NC; q += 256) {
        int s = q >> 7, c = q & 127;
        int idx = sel_idx_s[grp * SPB + s];
        int y = idx / WV, x = idx % WV;
        int yf = y >> 2; if (yf > HF - 1) yf = HF - 1;
        int xf = x >> 2; if (xf > WF - 1) xf = WF - 1;
        g[s][c] = features[((size_t)b * NC + c) * (HF * WF) + yf * WF + xf];
    }
    __syncthreads();

    if (tid < NC) {
        int d = tid;
        const float4* w4 = (const float4*)(proj_w + (size_t)d * NC);
        float acc[SPB];
        #pragma unroll
        for (int s = 0; s < SPB; ++s) acc[s] = 0.f;
        for (int q = 0; q < 32; ++q) {
            float4 wv = w4[q];
            #pragma unroll
            for (int s = 0; s < SPB; ++s) {
                float4 gv = *(const float4*)&g[s][4 * q];
                acc[s] += gv.x * wv.x;
                acc[s] += gv.y * wv.y;
                acc[s] += gv.z * wv.z;
                acc[s] += gv.w * wv.w;
            }
        }
        float bias = proj_b[d];
        #pragma unroll
        for (int s = 0; s < SPB; ++s) {
            int m = grp * SPB + s;
            out[((size_t)b * NSTORM + m) * NC + d] =
                sel_valid_s[m] ? (acc[s] + bias) : 0.f;
        }
    }
}

extern "C" void kernel_launch(void* const* d_in, const int* in_sizes, int n_in,
                              void* d_out, int out_size, void* d_ws, size_t ws_size,
                              hipStream_t stream) {
    const float* features = (const float*)d_in[0];
    const float* vil      = (const float*)d_in[1];
    const float* proj_w   = (const float*)d_in[2];
    const float* proj_b   = (const float*)d_in[3];
    float* out = (float*)d_out;

    uint8_t* ws = (uint8_t*)d_ws;
    int* tcnt      = (int*)ws;                        // 32*72 ints, all written
    uint64_t* cand = (uint64_t*)(ws + 32768);         // 32*72*256 u64 = 4.7 MB

    dim3 gA(GX, GY, NB);                   // 6 x 12 x 32
    peak_kernel<<<gA, 256, 0, stream>>>(vil, cand, tcnt);
    select_project_kernel<<<NPROJ, 256, 0, stream>>>(cand, tcnt, vil, features,
                                                     proj_w, proj_b, out);
}